// Round 4
// baseline (66.251 us; speedup 1.0000x reference)
//
#include <hip/hip_runtime.h>
#include <math.h>

#define BB 32
#define NN 512
#define NFEAT 128
#define NHID 8
#define NHEADS 8
#define LALPHA 0.2f

__device__ __forceinline__ float elu1(float x)  { return x > 0.f ? x : __expf(x) - 1.f; }

// monotone float -> uint mapping (total order refines float order); ok(-v) == ~ok(v)
__device__ __forceinline__ unsigned ordkey(float v) {
    unsigned u = __float_as_uint(v);
    return u ^ (((unsigned)((int)u >> 31)) | 0x80000000u);
}

// inclusive wave(64) scan
__device__ __forceinline__ float wscan(float x, int lane) {
    #pragma unroll
    for (int s = 1; s < 64; s <<= 1) {
        float y = __shfl_up(x, (unsigned)s, 64);
        x += (lane >= s) ? y : 0.f;
    }
    return x;
}

// Fused layer-1 GAT per (b,h). 1024 threads: t<512 "primary" (row t), t>=512 "helper" (row t-512).
__global__ __launch_bounds__(1024) void k12_gat1(
        const float* __restrict__ nf, const float* __restrict__ Ws,
        const float* __restrict__ As, float* __restrict__ x)
{
    __shared__ __align__(16) float WsL[NFEAT * NHID];          // 4 KB
    __shared__ float aL[16];
    __shared__ __align__(16) float whL[NN][NHID];              // 16 KB
    __shared__ __align__(16) float part[NN][NHID];             // 16 KB
    __shared__ __align__(16) unsigned long long key1[NN];      // 4 KB
    __shared__ __align__(16) unsigned long long key2[NN];      // 4 KB
    __shared__ float s1s[NN], s2s[NN];
    __shared__ int   idx2[NN];
    __shared__ float prefP[NN], prefQ[NN];
    __shared__ float den[NN];
    __shared__ __align__(16) float PP[NN][NHID];               // 16 KB
    __shared__ __align__(16) float QQ[NN][NHID];               // 16 KB
    __shared__ float wT[16][NHID];
    __shared__ __align__(16) int cnt[NN][4];                   // 8 KB

    const int bh = blockIdx.x, b = bh >> 3, h = bh & 7;
    const int t = threadIdx.x;
    const int lane = t & 63, w = t >> 6;
    const int r = t & (NN - 1);
    const bool hi = t >= NN;

    if (t < 256) ((float4*)WsL)[t] = ((const float4*)(Ws + (size_t)h * NFEAT * NHID))[t];
    if (t < 16) aL[t] = As[h * 16 + t];
    __syncthreads();                                           // S1

    // ---- matmul halves: primary cols [0,64), helper cols [64,128) ----
    float acc[NHID];
    {
        #pragma unroll
        for (int d = 0; d < NHID; ++d) acc[d] = 0.f;
        const float4* row = (const float4*)(nf + ((size_t)b * NN + r) * NFEAT + (hi ? 64 : 0));
        const float* wbase = &WsL[(hi ? 64 : 0) * NHID];
        #pragma unroll 8
        for (int f4 = 0; f4 < 16; ++f4) {
            float4 v = row[f4];
            const float* w0 = wbase + (f4 * 4 + 0) * NHID;
            const float* w1 = wbase + (f4 * 4 + 1) * NHID;
            const float* w2 = wbase + (f4 * 4 + 2) * NHID;
            const float* w3 = wbase + (f4 * 4 + 3) * NHID;
            #pragma unroll
            for (int d = 0; d < NHID; ++d)
                acc[d] += v.x * w0[d] + v.y * w1[d] + v.z * w2[d] + v.w * w3[d];
        }
        if (hi) {
            float4* pp = (float4*)&part[r][0];
            pp[0] = make_float4(acc[0], acc[1], acc[2], acc[3]);
            pp[1] = make_float4(acc[4], acc[5], acc[6], acc[7]);
        }
    }
    __syncthreads();                                           // S2

    float v1 = 0.f, v2 = 0.f;
    if (!hi) {
        #pragma unroll
        for (int d = 0; d < NHID; ++d) acc[d] += part[t][d];
        float a1 = 0.f, a2 = 0.f;
        #pragma unroll
        for (int d = 0; d < NHID; ++d) { a1 += acc[d] * aL[d]; a2 += acc[d] * aL[8 + d]; }
        v1 = a1; v2 = a2;
        float4* wr = (float4*)&whL[t][0];
        wr[0] = make_float4(acc[0], acc[1], acc[2], acc[3]);
        wr[1] = make_float4(acc[4], acc[5], acc[6], acc[7]);
        key1[t] = (((unsigned long long)ordkey(v1)) << 9) | (unsigned)t;
        key2[t] = (((unsigned long long)ordkey(v2)) << 9) | (unsigned)t;
    }
    __syncthreads();                                           // S3

    // ---- rank + threshold counts, each thread covers half the range for row r ----
    int r1, r2, c3, c4;
    {
        const unsigned long long m1 = key1[r], m2 = key2[r];
        const unsigned long long M3 = ((unsigned long long)(~(unsigned)(m2 >> 9))) << 9; // ok(-v2)<<9
        const unsigned long long M4 = ((unsigned long long)(~(unsigned)(m1 >> 9))) << 9; // ok(-v1)<<9
        int a1 = 0, a2 = 0, a3 = 0, a4 = 0;
        const ulonglong2* k1p = (const ulonglong2*)(key1 + (hi ? NN / 2 : 0));
        const ulonglong2* k2p = (const ulonglong2*)(key2 + (hi ? NN / 2 : 0));
        #pragma unroll 4
        for (int k = 0; k < NN / 4; ++k) {
            ulonglong2 u1 = k1p[k];
            ulonglong2 u2 = k2p[k];
            a1 += (u1.x < m1) + (u1.y < m1);
            a2 += (u2.x < m2) + (u2.y < m2);
            a3 += (u1.x < M3) + (u1.y < M3);
            a4 += (u2.x < M4) + (u2.y < M4);
        }
        if (hi) { cnt[r][0] = a1; cnt[r][1] = a2; cnt[r][2] = a3; cnt[r][3] = a4; }
        r1 = a1; r2 = a2; c3 = a3; c4 = a4;
    }
    __syncthreads();                                           // S4

    if (!hi) {
        r1 += cnt[t][0]; r2 += cnt[t][1]; c3 += cnt[t][2]; c4 += cnt[t][3];
        s1s[r1] = v1;
        s2s[r2] = v2;
        idx2[r2] = t;
    }
    __syncthreads();                                           // S5

    // ---- exp scans over sorted s1 (primaries, 8 waves) ----
    float ps = 0.f, qs = 0.f;
    if (!hi) {
        ps = wscan(__expf(s1s[t]), lane);
        qs = wscan(__expf(0.2f * s1s[t]), lane);
        if (lane == 63) { wT[w][0] = ps; wT[w][1] = qs; }
    }
    __syncthreads();                                           // S6

    float TP = 0.f;
    if (!hi) {
        float offp = 0.f, offq = 0.f;
        #pragma unroll
        for (int ww = 0; ww < 8; ++ww) {
            float tp = wT[ww][0], tq = wT[ww][1];
            TP += tp;
            if (ww < w) { offp += tp; offq += tq; }
        }
        prefP[t] = ps + offp;
        prefQ[t] = qs + offq;
    }
    __syncthreads();                                           // S7

    if (!hi) {
        const float pk = (c3 > 0) ? prefP[c3 - 1] : 0.f;
        const float qk = (c3 > 0) ? prefQ[c3 - 1] : 0.f;
        den[t] = __expf(v2) * (TP - pk) + __expf(0.2f * v2) * qk;
    }
    __syncthreads();                                           // S8

    // ---- payload at sorted s2 pos r: primary scans P comps, helper scans Q comps ----
    float pv[NHID];
    {
        const int j = idx2[r];
        const float key = s2s[r];
        const float invd = 1.f / den[j];
        const float sc = (hi ? __expf(0.2f * key) : __expf(key)) * invd;
        const float4 w0 = ((const float4*)&whL[j][0])[0];
        const float4 w1 = ((const float4*)&whL[j][0])[1];
        pv[0] = sc * w0.x; pv[1] = sc * w0.y; pv[2] = sc * w0.z; pv[3] = sc * w0.w;
        pv[4] = sc * w1.x; pv[5] = sc * w1.y; pv[6] = sc * w1.z; pv[7] = sc * w1.w;
    }
    #pragma unroll
    for (int c = 0; c < NHID; ++c) pv[c] = wscan(pv[c], lane);
    if (lane == 63) {
        #pragma unroll
        for (int c = 0; c < NHID; ++c) wT[w][c] = pv[c];
    }
    __syncthreads();                                           // S9

    float totP[NHID];
    {
        const int wbase = hi ? 8 : 0;
        float off[NHID];
        #pragma unroll
        for (int c = 0; c < NHID; ++c) { off[c] = 0.f; totP[c] = 0.f; }
        #pragma unroll
        for (int ww = 0; ww < 8; ++ww) {
            #pragma unroll
            for (int c = 0; c < NHID; ++c) {
                float tp = wT[wbase + ww][c];
                totP[c] += tp;                     // for primaries this is total P
                if (wbase + ww < w) off[c] += tp;
            }
        }
        #pragma unroll
        for (int c = 0; c < NHID; ++c) pv[c] += off[c];
        float4* dst = hi ? (float4*)&QQ[r][0] : (float4*)&PP[r][0];
        dst[0] = make_float4(pv[0], pv[1], pv[2], pv[3]);
        dst[1] = make_float4(pv[4], pv[5], pv[6], pv[7]);
    }
    __syncthreads();                                           // S10

    // ---- row output (primaries) ----
    if (!hi) {
        const float p1 = __expf(v1), q1 = __expf(0.2f * v1);
        float4 P0, P1, Q0, Q1;
        if (c4 > 0) {
            const float4* pp4 = (const float4*)&PP[c4 - 1][0];
            const float4* qq4 = (const float4*)&QQ[c4 - 1][0];
            P0 = pp4[0]; P1 = pp4[1]; Q0 = qq4[0]; Q1 = qq4[1];
        } else {
            P0 = P1 = Q0 = Q1 = make_float4(0.f, 0.f, 0.f, 0.f);
        }
        float h0 = p1 * (totP[0] - P0.x) + q1 * Q0.x;
        float h1 = p1 * (totP[1] - P0.y) + q1 * Q0.y;
        float h2 = p1 * (totP[2] - P0.z) + q1 * Q0.z;
        float h3 = p1 * (totP[3] - P0.w) + q1 * Q0.w;
        float h4 = p1 * (totP[4] - P1.x) + q1 * Q1.x;
        float h5 = p1 * (totP[5] - P1.y) + q1 * Q1.y;
        float h6 = p1 * (totP[6] - P1.z) + q1 * Q1.z;
        float h7 = p1 * (totP[7] - P1.w) + q1 * Q1.w;
        float* xp = x + ((size_t)(b * NN + t)) * (NHEADS * NHID) + h * NHID;
        ((float4*)xp)[0] = make_float4(elu1(h0), elu1(h1), elu1(h2), elu1(h3));
        ((float4*)xp)[1] = make_float4(elu1(h4), elu1(h5), elu1(h6), elu1(h7));
    }
}

// Tail per batch b: Wh2 = x@W_out, factorized dens, row-0 attention, elu, MLP head.
__global__ __launch_bounds__(1024) void k34_tail(
        const float* __restrict__ x, const float* __restrict__ Wout,
        const float* __restrict__ aout, const float* __restrict__ feats,
        const float* __restrict__ l1w, const float* __restrict__ l1b,
        const float* __restrict__ pa, const float* __restrict__ gma,
        const float* __restrict__ bta, const float* __restrict__ l2w,
        const float* __restrict__ l2b, float* __restrict__ out)
{
    __shared__ __align__(16) float WL[64 * NHID];              // 2 KB
    __shared__ float aL[16];
    __shared__ __align__(16) float wh2[NN][NHID];              // 16 KB
    __shared__ __align__(16) float part[NN][NHID];             // 16 KB
    __shared__ __align__(16) unsigned long long key1[NN];      // 4 KB
    __shared__ unsigned key2v[NN];                             // 2 KB
    __shared__ float s1s[NN], prefP[NN], prefQ[NN];
    __shared__ __align__(8) int cnt[NN][2];                    // 4 KB
    __shared__ float wT[8][2];
    __shared__ float wR[8][NHID];
    __shared__ float gatL[NHID];
    __shared__ float zL[NHID];
    __shared__ float s1zeroL;

    const int b = blockIdx.x, t = threadIdx.x;
    const int lane = t & 63, w = t >> 6;
    const int r = t & (NN - 1);
    const bool hi = t >= NN;

    if (t < 128) ((float4*)WL)[t] = ((const float4*)Wout)[t];
    if (t < 16) aL[t] = aout[t];
    __syncthreads();                                           // S1

    // matmul halves: primary cols [0,32), helper cols [32,64)
    float acc[NHID];
    {
        #pragma unroll
        for (int d = 0; d < NHID; ++d) acc[d] = 0.f;
        const float4* row = (const float4*)(x + ((size_t)b * NN + r) * (NHEADS * NHID) + (hi ? 32 : 0));
        const float* wbase = &WL[(hi ? 32 : 0) * NHID];
        #pragma unroll 4
        for (int k4 = 0; k4 < 8; ++k4) {
            float4 v = row[k4];
            const float* w0 = wbase + (k4 * 4 + 0) * NHID;
            const float* w1 = wbase + (k4 * 4 + 1) * NHID;
            const float* w2 = wbase + (k4 * 4 + 2) * NHID;
            const float* w3 = wbase + (k4 * 4 + 3) * NHID;
            #pragma unroll
            for (int d = 0; d < NHID; ++d)
                acc[d] += v.x * w0[d] + v.y * w1[d] + v.z * w2[d] + v.w * w3[d];
        }
        if (hi) {
            float4* pp = (float4*)&part[r][0];
            pp[0] = make_float4(acc[0], acc[1], acc[2], acc[3]);
            pp[1] = make_float4(acc[4], acc[5], acc[6], acc[7]);
        }
    }
    __syncthreads();                                           // S2

    float v1 = 0.f, v2 = 0.f;
    if (!hi) {
        #pragma unroll
        for (int d = 0; d < NHID; ++d) acc[d] += part[t][d];
        float a1 = 0.f, a2 = 0.f;
        #pragma unroll
        for (int d = 0; d < NHID; ++d) { a1 += acc[d] * aL[d]; a2 += acc[d] * aL[8 + d]; }
        v1 = a1; v2 = a2;
        float4* wr = (float4*)&wh2[t][0];
        wr[0] = make_float4(acc[0], acc[1], acc[2], acc[3]);
        wr[1] = make_float4(acc[4], acc[5], acc[6], acc[7]);
        key1[t] = (((unsigned long long)ordkey(v1)) << 9) | (unsigned)t;
        key2v[t] = ordkey(v2);
        if (t == 0) s1zeroL = v1;
    }
    __syncthreads();                                           // S3

    // rank of s1 + threshold count c3 = #{s1 < -v2}, half-range each
    int r1, c3;
    {
        const unsigned long long m1 = key1[r];
        const unsigned long long M3 = ((unsigned long long)(~key2v[r])) << 9;
        int a1 = 0, a3 = 0;
        const ulonglong2* k1p = (const ulonglong2*)(key1 + (hi ? NN / 2 : 0));
        #pragma unroll 4
        for (int k = 0; k < NN / 4; ++k) {
            ulonglong2 u = k1p[k];
            a1 += (u.x < m1) + (u.y < m1);
            a3 += (u.x < M3) + (u.y < M3);
        }
        if (hi) { cnt[r][0] = a1; cnt[r][1] = a3; }
        r1 = a1; c3 = a3;
    }
    __syncthreads();                                           // S4

    if (!hi) {
        r1 += cnt[t][0]; c3 += cnt[t][1];
        s1s[r1] = v1;
    }
    __syncthreads();                                           // S5

    float ps = 0.f, qs = 0.f;
    if (!hi) {
        ps = wscan(__expf(s1s[t]), lane);
        qs = wscan(__expf(0.2f * s1s[t]), lane);
        if (lane == 63) { wT[w][0] = ps; wT[w][1] = qs; }
    }
    __syncthreads();                                           // S6

    float TP = 0.f;
    if (!hi) {
        float offp = 0.f, offq = 0.f;
        #pragma unroll
        for (int ww = 0; ww < 8; ++ww) {
            float tp = wT[ww][0], tq = wT[ww][1];
            TP += tp;
            if (ww < w) { offp += tp; offq += tq; }
        }
        prefP[t] = ps + offp;
        prefQ[t] = qs + offq;
    }
    __syncthreads();                                           // S7

    // den, row-0 weight, weighted reduce
    if (!hi) {
        const float pk = (c3 > 0) ? prefP[c3 - 1] : 0.f;
        const float qk = (c3 > 0) ? prefQ[c3 - 1] : 0.f;
        const float dj = __expf(v2) * (TP - pk) + __expf(0.2f * v2) * qk;
        float e0 = s1zeroL + v2;
        e0 = e0 >= 0.f ? e0 : LALPHA * e0;
        const float wgt = __expf(e0) / dj;
        #pragma unroll
        for (int d = 0; d < NHID; ++d) acc[d] = wgt * wh2[t][d];
        #pragma unroll
        for (int s = 1; s < 64; s <<= 1) {
            #pragma unroll
            for (int d = 0; d < NHID; ++d) acc[d] += __shfl_xor(acc[d], s, 64);
        }
        if (lane == 0) {
            #pragma unroll
            for (int d = 0; d < NHID; ++d) wR[w][d] = acc[d];
        }
    }
    __syncthreads();                                           // S8

    if (t < NHID) {
        float g = 0.f;
        #pragma unroll
        for (int ww = 0; ww < 8; ++ww) g += wR[ww][t];
        gatL[t] = elu1(g);
    }
    __syncthreads();                                           // S9

    if (t < NHID) {
        const float* wv = l1w + t * (NFEAT + NHID);
        float z = l1b[t];
        for (int k = 0; k < NFEAT; ++k) z += feats[b * NFEAT + k] * wv[k];
        #pragma unroll
        for (int k = 0; k < NHID; ++k) z += gatL[k] * wv[NFEAT + k];
        const float a = pa[0];
        z = z >= 0.f ? z : a * z;
        z = z * (1.f / sqrtf(1.f + 1e-5f)) * gma[t] + bta[t];
        zL[t] = z;
    }
    __syncthreads();                                           // S10
    if (t == 0) {
        float o = l2b[0];
        #pragma unroll
        for (int d = 0; d < NHID; ++d) o += zL[d] * l2w[d];
        out[b] = o;
    }
}

extern "C" void kernel_launch(void* const* d_in, const int* in_sizes, int n_in,
                              void* d_out, int out_size, void* d_ws, size_t ws_size,
                              hipStream_t stream) {
    const float* feats = (const float*)d_in[0];
    const float* nf    = (const float*)d_in[1];
    const float* Ws    = (const float*)d_in[2];
    const float* As    = (const float*)d_in[3];
    const float* Wout  = (const float*)d_in[4];
    const float* aout  = (const float*)d_in[5];
    const float* l1w   = (const float*)d_in[6];
    const float* l1b   = (const float*)d_in[7];
    const float* pa    = (const float*)d_in[8];
    const float* gma   = (const float*)d_in[9];
    const float* bta   = (const float*)d_in[10];
    const float* l2w   = (const float*)d_in[11];
    const float* l2b   = (const float*)d_in[12];
    float* out = (float*)d_out;

    float* x = (float*)d_ws;   // 32*512*64 floats = 4 MB

    k12_gat1<<<BB * NHEADS, 1024, 0, stream>>>(nf, Ws, As, x);
    k34_tail<<<BB, 1024, 0, stream>>>(x, Wout, aout, feats, l1w, l1b, pa, gma, bta, l2w, l2b, out);
}

// Round 5
// 51.093 us; speedup vs baseline: 1.2967x; 1.2967x over previous
//
#include <hip/hip_runtime.h>
#include <math.h>

#define BB 32
#define NN 512
#define NFEAT 128
#define NHID 8
#define NHEADS 8
#define LALPHA 0.2f

__device__ __forceinline__ float elu1(float x)  { return x > 0.f ? x : __expf(x) - 1.f; }

// monotone float -> uint mapping (total order refines float order); ok(-v) == ~ok(v)
__device__ __forceinline__ unsigned ordkey(float v) {
    unsigned u = __float_as_uint(v);
    return u ^ (((unsigned)((int)u >> 31)) | 0x80000000u);
}
__device__ __forceinline__ float unord(unsigned k) {
    unsigned u = (k & 0x80000000u) ? (k ^ 0x80000000u) : ~k;
    return __uint_as_float(u);
}

// first index k in [0,512] with a[k] >= v (a ascending)
__device__ __forceinline__ int lb512(const float* a, float v) {
    int lo = 0, hi = NN;
    while (lo < hi) {
        int m = (lo + hi) >> 1;
        if (a[m] < v) lo = m + 1; else hi = m;
    }
    return lo;
}

// inclusive wave(64) scan
__device__ __forceinline__ float wscan(float x, int lane) {
    #pragma unroll
    for (int s = 1; s < 64; s <<= 1) {
        float y = __shfl_up(x, (unsigned)s, 64);
        x += (lane >= s) ? y : 0.f;
    }
    return x;
}

// Fused layer-1 GAT per (b,h). 1024 threads: P (t<512) and H (t>=512) do DIFFERENT phases.
__global__ __launch_bounds__(1024) void k12_gat1(
        const float* __restrict__ nf, const float* __restrict__ Ws,
        const float* __restrict__ As, float* __restrict__ x)
{
    __shared__ __align__(16) float WT[NHID * NFEAT];           // transposed W: [d][f], 4 KB
    __shared__ float aL[16];
    __shared__ __align__(16) float whL[NN][NHID];              // 16 KB
    __shared__ __align__(16) float part[NN][NHID];             // 16 KB
    __shared__ __align__(16) unsigned long long key1[NN];      // 4 KB
    __shared__ __align__(16) unsigned long long key2[NN];      // 4 KB
    __shared__ float s1s[NN], s2s[NN];
    __shared__ int   idx2[NN];
    __shared__ float prefP[NN], prefQ[NN], denS[NN];
    __shared__ __align__(16) float PP[NN][NHID];               // 16 KB
    __shared__ __align__(16) float QQ[NN][NHID];               // 16 KB
    __shared__ float wT[16][NHID];

    const int blk = blockIdx.x;
    const int b = blk & 31, h = blk >> 5;   // same-b blocks share an XCD (blk%8 == b%8)
    const int t = threadIdx.x;
    const int r = t & (NN - 1);
    const bool hi = t >= NN;
    const int lane = t & 63, w = t >> 6;

    // WT[d][f] = Ws[h][f][d]
    {
        const int f = t >> 3, d = t & 7;
        WT[d * NFEAT + f] = Ws[(size_t)h * NFEAT * NHID + t];
    }
    if (t < 16) aL[t] = As[h * 16 + t];
    __syncthreads();                                           // B1

    // ---- matmul, split K: P cols [0,64), H cols [64,128) ----
    float acc[NHID];
    {
        #pragma unroll
        for (int d = 0; d < NHID; ++d) acc[d] = 0.f;
        const float4* row = (const float4*)(nf + ((size_t)b * NN + r) * NFEAT + (hi ? 64 : 0));
        const int fb = hi ? 16 : 0;
        const float4* WT4 = (const float4*)WT;
        #pragma unroll 4
        for (int f4 = 0; f4 < 16; ++f4) {
            float4 v = row[f4];
            #pragma unroll
            for (int d = 0; d < NHID; ++d) {
                float4 wv = WT4[d * 32 + fb + f4];
                acc[d] += v.x * wv.x + v.y * wv.y + v.z * wv.z + v.w * wv.w;
            }
        }
        if (hi) {
            float4* pp = (float4*)&part[r][0];
            pp[0] = make_float4(acc[0], acc[1], acc[2], acc[3]);
            pp[1] = make_float4(acc[4], acc[5], acc[6], acc[7]);
        }
    }
    __syncthreads();                                           // B2

    float v1 = 0.f;
    if (!hi) {
        #pragma unroll
        for (int d = 0; d < NHID; ++d) acc[d] += part[t][d];
        float a1 = 0.f, a2 = 0.f;
        #pragma unroll
        for (int d = 0; d < NHID; ++d) { a1 += acc[d] * aL[d]; a2 += acc[d] * aL[8 + d]; }
        v1 = a1;
        float4* wr = (float4*)&whL[t][0];
        wr[0] = make_float4(acc[0], acc[1], acc[2], acc[3]);
        wr[1] = make_float4(acc[4], acc[5], acc[6], acc[7]);
        key1[t] = (((unsigned long long)ordkey(a1)) << 9) | (unsigned)t;
        key2[t] = (((unsigned long long)ordkey(a2)) << 9) | (unsigned)t;
    }
    __syncthreads();                                           // B3

    // ---- rank-count: P ranks key1 -> s1s; H ranks key2 -> s2s/idx2 ----
    {
        const unsigned long long* karr = hi ? key2 : key1;
        const unsigned long long m = karr[r];
        int rk = 0;
        const ulonglong2* kp = (const ulonglong2*)karr;
        #pragma unroll 8
        for (int k = 0; k < NN / 2; ++k) {
            ulonglong2 u = kp[k];
            rk += (u.x < m) + (u.y < m);
        }
        if (!hi) s1s[rk] = v1;
        else { s2s[rk] = unord((unsigned)(m >> 9)); idx2[rk] = r; }
    }
    __syncthreads();                                           // B4

    // ---- P: exp wave-scans over sorted s1; H: prefetch own payload row ----
    float ps = 0.f, qs = 0.f;
    float whr[NHID];
    float s2r = 0.f;
    if (!hi) {
        ps = wscan(__expf(s1s[t]), lane);
        qs = wscan(__expf(0.2f * s1s[t]), lane);
        if (lane == 63) { wT[w][0] = ps; wT[w][1] = qs; }
    } else {
        const int j = idx2[r];
        s2r = s2s[r];
        const float4 w0 = ((const float4*)&whL[j][0])[0];
        const float4 w1 = ((const float4*)&whL[j][0])[1];
        whr[0] = w0.x; whr[1] = w0.y; whr[2] = w0.z; whr[3] = w0.w;
        whr[4] = w1.x; whr[5] = w1.y; whr[6] = w1.z; whr[7] = w1.w;
    }
    __syncthreads();                                           // B5

    // ---- P: finalize prefixes + own c4 search; H: own c3 search ----
    int c4 = 0, kH = 0;
    float e1p = 0.f, e1q = 0.f;
    if (!hi) {
        float offp = 0.f, offq = 0.f;
        #pragma unroll
        for (int ww = 0; ww < 8; ++ww) {
            float tp = wT[ww][0], tq = wT[ww][1];
            if (ww < w) { offp += tp; offq += tq; }
        }
        prefP[t] = ps + offp;
        prefQ[t] = qs + offq;
        c4 = lb512(s2s, -v1);
        e1p = __expf(v1); e1q = __expf(0.2f * v1);
    } else {
        kH = lb512(s1s, -s2r);
    }
    __syncthreads();                                           // B6

    // ---- H: denominators (sorted order) ----
    if (hi) {
        const float TPh = prefP[NN - 1];
        const float pk = (kH > 0) ? prefP[kH - 1] : 0.f;
        const float qk = (kH > 0) ? prefQ[kH - 1] : 0.f;
        denS[r] = __expf(s2r) * (TPh - pk) + __expf(0.2f * s2r) * qk;
    }
    __syncthreads();                                           // B7

    // ---- payload scans: P scans P-components, H scans Q-components ----
    float pv[NHID];
    if (!hi) {
        const float s2p = s2s[t];
        const float invd = 1.f / denS[t];
        const int j = idx2[t];
        const float pw = __expf(s2p) * invd;
        const float4 w0 = ((const float4*)&whL[j][0])[0];
        const float4 w1 = ((const float4*)&whL[j][0])[1];
        pv[0] = pw * w0.x; pv[1] = pw * w0.y; pv[2] = pw * w0.z; pv[3] = pw * w0.w;
        pv[4] = pw * w1.x; pv[5] = pw * w1.y; pv[6] = pw * w1.z; pv[7] = pw * w1.w;
    } else {
        const float qw = __expf(0.2f * s2r) / denS[r];
        #pragma unroll
        for (int c = 0; c < NHID; ++c) pv[c] = qw * whr[c];
    }
    #pragma unroll
    for (int c = 0; c < NHID; ++c) pv[c] = wscan(pv[c], lane);
    if (lane == 63) {
        #pragma unroll
        for (int c = 0; c < NHID; ++c) wT[w][c] = pv[c];
    }
    __syncthreads();                                           // B8

    // ---- cross-wave offsets; write PP / QQ ----
    float totP[NHID];
    {
        const int wb = hi ? 8 : 0;
        float off[NHID];
        #pragma unroll
        for (int c = 0; c < NHID; ++c) { off[c] = 0.f; totP[c] = 0.f; }
        #pragma unroll
        for (int ww = 0; ww < 8; ++ww) {
            #pragma unroll
            for (int c = 0; c < NHID; ++c) {
                float tp = wT[wb + ww][c];
                totP[c] += tp;
                if (wb + ww < w) off[c] += tp;
            }
        }
        #pragma unroll
        for (int c = 0; c < NHID; ++c) pv[c] += off[c];
        float4* dst = hi ? (float4*)&QQ[r][0] : (float4*)&PP[r][0];
        dst[0] = make_float4(pv[0], pv[1], pv[2], pv[3]);
        dst[1] = make_float4(pv[4], pv[5], pv[6], pv[7]);
    }
    __syncthreads();                                           // B9

    // ---- P: row outputs ----
    if (!hi) {
        float4 P0, P1, Q0, Q1;
        if (c4 > 0) {
            const float4* pp4 = (const float4*)&PP[c4 - 1][0];
            const float4* qq4 = (const float4*)&QQ[c4 - 1][0];
            P0 = pp4[0]; P1 = pp4[1]; Q0 = qq4[0]; Q1 = qq4[1];
        } else {
            P0 = P1 = Q0 = Q1 = make_float4(0.f, 0.f, 0.f, 0.f);
        }
        float h0 = e1p * (totP[0] - P0.x) + e1q * Q0.x;
        float h1 = e1p * (totP[1] - P0.y) + e1q * Q0.y;
        float h2 = e1p * (totP[2] - P0.z) + e1q * Q0.z;
        float h3 = e1p * (totP[3] - P0.w) + e1q * Q0.w;
        float h4 = e1p * (totP[4] - P1.x) + e1q * Q1.x;
        float h5 = e1p * (totP[5] - P1.y) + e1q * Q1.y;
        float h6 = e1p * (totP[6] - P1.z) + e1q * Q1.z;
        float h7 = e1p * (totP[7] - P1.w) + e1q * Q1.w;
        float* xp = x + ((size_t)(b * NN + t)) * (NHEADS * NHID) + h * NHID;
        ((float4*)xp)[0] = make_float4(elu1(h0), elu1(h1), elu1(h2), elu1(h3));
        ((float4*)xp)[1] = make_float4(elu1(h4), elu1(h5), elu1(h6), elu1(h7));
    }
}

// Tail per batch b: Wh2 = x@W_out; P ranks s1 while H counts c3; row-0 attention; head MLP.
__global__ __launch_bounds__(1024) void k34_tail(
        const float* __restrict__ x, const float* __restrict__ Wout,
        const float* __restrict__ aout, const float* __restrict__ feats,
        const float* __restrict__ l1w, const float* __restrict__ l1b,
        const float* __restrict__ pa, const float* __restrict__ gma,
        const float* __restrict__ bta, const float* __restrict__ l2w,
        const float* __restrict__ l2b, float* __restrict__ out)
{
    __shared__ __align__(16) float WLT[NHID * 64];             // transposed W_out [d][f], 2 KB
    __shared__ float aL[16];
    __shared__ __align__(16) float wh2[NN][NHID];              // 16 KB
    __shared__ __align__(16) float part[NN][NHID];             // 16 KB
    __shared__ __align__(16) unsigned long long key1[NN];      // 4 KB
    __shared__ float s2L[NN];
    __shared__ float s1s[NN], prefP[NN], prefQ[NN];
    __shared__ float wT[8][2];
    __shared__ float wR[8][NHID];
    __shared__ float hp[2][NHID];
    __shared__ float gatL[NHID];
    __shared__ float zL[NHID];
    __shared__ float s1zero;

    const int b = blockIdx.x, t = threadIdx.x;
    const int r = t & (NN - 1);
    const bool hi = t >= NN;
    const int lane = t & 63, w = t >> 6;

    if (t < 512) {
        const int f = t >> 3, d = t & 7;
        WLT[d * 64 + f] = Wout[t];
    }
    if (t < 16) aL[t] = aout[t];
    __syncthreads();                                           // B1

    // matmul, split K: P cols [0,32), H cols [32,64)
    float acc[NHID];
    {
        #pragma unroll
        for (int d = 0; d < NHID; ++d) acc[d] = 0.f;
        const float4* row = (const float4*)(x + ((size_t)b * NN + r) * (NHEADS * NHID) + (hi ? 32 : 0));
        const int fb = hi ? 8 : 0;
        const float4* WT4 = (const float4*)WLT;
        #pragma unroll 4
        for (int f4 = 0; f4 < 8; ++f4) {
            float4 v = row[f4];
            #pragma unroll
            for (int d = 0; d < NHID; ++d) {
                float4 wv = WT4[d * 16 + fb + f4];
                acc[d] += v.x * wv.x + v.y * wv.y + v.z * wv.z + v.w * wv.w;
            }
        }
        if (hi) {
            float4* pp = (float4*)&part[r][0];
            pp[0] = make_float4(acc[0], acc[1], acc[2], acc[3]);
            pp[1] = make_float4(acc[4], acc[5], acc[6], acc[7]);
        }
    }
    __syncthreads();                                           // B2

    float v1 = 0.f;
    if (!hi) {
        #pragma unroll
        for (int d = 0; d < NHID; ++d) acc[d] += part[t][d];
        float a1 = 0.f, a2 = 0.f;
        #pragma unroll
        for (int d = 0; d < NHID; ++d) { a1 += acc[d] * aL[d]; a2 += acc[d] * aL[8 + d]; }
        v1 = a1;
        float4* wr = (float4*)&wh2[t][0];
        wr[0] = make_float4(acc[0], acc[1], acc[2], acc[3]);
        wr[1] = make_float4(acc[4], acc[5], acc[6], acc[7]);
        key1[t] = (((unsigned long long)ordkey(a1)) << 9) | (unsigned)t;
        s2L[t] = a2;
        if (t == 0) s1zero = a1;
    }
    __syncthreads();                                           // B3

    // P: rank s1 -> s1s;  H: c3 = #{s1 < -v2} fused count
    int c3 = 0; float v2h = 0.f;
    {
        const ulonglong2* kp = (const ulonglong2*)key1;
        if (!hi) {
            const unsigned long long m = key1[t];
            int rk = 0;
            #pragma unroll 8
            for (int k = 0; k < NN / 2; ++k) {
                ulonglong2 u = kp[k];
                rk += (u.x < m) + (u.y < m);
            }
            s1s[rk] = v1;
        } else {
            v2h = s2L[r];
            const unsigned long long M3 = ((unsigned long long)(~ordkey(v2h))) << 9;
            int a3 = 0;
            #pragma unroll 8
            for (int k = 0; k < NN / 2; ++k) {
                ulonglong2 u = kp[k];
                a3 += (u.x < M3) + (u.y < M3);
            }
            c3 = a3;
        }
    }
    __syncthreads();                                           // B4

    float ps = 0.f, qs = 0.f;
    if (!hi) {
        ps = wscan(__expf(s1s[t]), lane);
        qs = wscan(__expf(0.2f * s1s[t]), lane);
        if (lane == 63) { wT[w][0] = ps; wT[w][1] = qs; }
    }
    __syncthreads();                                           // B5

    if (!hi) {
        float offp = 0.f, offq = 0.f;
        #pragma unroll
        for (int ww = 0; ww < 8; ++ww) {
            float tp = wT[ww][0], tq = wT[ww][1];
            if (ww < w) { offp += tp; offq += tq; }
        }
        prefP[t] = ps + offp;
        prefQ[t] = qs + offq;
    }
    __syncthreads();                                           // B6

    // H: den + row-0 weight + weighted wave-reduce;  P(t<128): head feats dot
    if (hi) {
        const float TPh = prefP[NN - 1];
        const float pk = (c3 > 0) ? prefP[c3 - 1] : 0.f;
        const float qk = (c3 > 0) ? prefQ[c3 - 1] : 0.f;
        const float dj = __expf(v2h) * (TPh - pk) + __expf(0.2f * v2h) * qk;
        float e0 = s1zero + v2h;
        e0 = e0 >= 0.f ? e0 : LALPHA * e0;
        const float wgt = __expf(e0) / dj;
        float a[NHID];
        const float4 q0 = ((const float4*)&wh2[r][0])[0];
        const float4 q1 = ((const float4*)&wh2[r][0])[1];
        a[0] = wgt * q0.x; a[1] = wgt * q0.y; a[2] = wgt * q0.z; a[3] = wgt * q0.w;
        a[4] = wgt * q1.x; a[5] = wgt * q1.y; a[6] = wgt * q1.z; a[7] = wgt * q1.w;
        #pragma unroll
        for (int s = 1; s < 64; s <<= 1) {
            #pragma unroll
            for (int d = 0; d < NHID; ++d) a[d] += __shfl_xor(a[d], s, 64);
        }
        if (lane == 0) {
            #pragma unroll
            for (int d = 0; d < NHID; ++d) wR[w - 8][d] = a[d];
        }
    } else if (t < 128) {
        const float fk = feats[b * NFEAT + t];
        #pragma unroll
        for (int d = 0; d < NHID; ++d) {
            float p = fk * l1w[d * (NFEAT + NHID) + t];
            #pragma unroll
            for (int s = 1; s < 64; s <<= 1) p += __shfl_xor(p, s, 64);
            if (lane == 0) hp[w][d] = p;
        }
    }
    __syncthreads();                                           // B7

    if (t < NHID) {
        float g = 0.f;
        #pragma unroll
        for (int ww = 0; ww < 8; ++ww) g += wR[ww][t];
        gatL[t] = elu1(g);
    }
    __syncthreads();                                           // B8

    if (t < NHID) {
        const float* wv = l1w + t * (NFEAT + NHID);
        float z = l1b[t] + hp[0][t] + hp[1][t];
        #pragma unroll
        for (int k = 0; k < NHID; ++k) z += gatL[k] * wv[NFEAT + k];
        const float a = pa[0];
        z = z >= 0.f ? z : a * z;
        z = z * (1.f / sqrtf(1.f + 1e-5f)) * gma[t] + bta[t];
        zL[t] = z;
    }
    __syncthreads();                                           // B9
    if (t == 0) {
        float o = l2b[0];
        #pragma unroll
        for (int d = 0; d < NHID; ++d) o += zL[d] * l2w[d];
        out[b] = o;
    }
}

extern "C" void kernel_launch(void* const* d_in, const int* in_sizes, int n_in,
                              void* d_out, int out_size, void* d_ws, size_t ws_size,
                              hipStream_t stream) {
    const float* feats = (const float*)d_in[0];
    const float* nf    = (const float*)d_in[1];
    const float* Ws    = (const float*)d_in[2];
    const float* As    = (const float*)d_in[3];
    const float* Wout  = (const float*)d_in[4];
    const float* aout  = (const float*)d_in[5];
    const float* l1w   = (const float*)d_in[6];
    const float* l1b   = (const float*)d_in[7];
    const float* pa    = (const float*)d_in[8];
    const float* gma   = (const float*)d_in[9];
    const float* bta   = (const float*)d_in[10];
    const float* l2w   = (const float*)d_in[11];
    const float* l2b   = (const float*)d_in[12];
    float* out = (float*)d_out;

    float* x = (float*)d_ws;   // 32*512*64 floats = 4 MB

    k12_gat1<<<BB * NHEADS, 1024, 0, stream>>>(nf, Ws, As, x);
    k34_tail<<<BB, 1024, 0, stream>>>(x, Wout, aout, feats, l1w, l1b, pa, gma, bta, l2w, l2b, out);
}

// Round 6
// 40.162 us; speedup vs baseline: 1.6496x; 1.2722x over previous
//
#include <hip/hip_runtime.h>
#include <math.h>

#define BB 32
#define NN 512
#define NFEAT 128
#define NHID 8
#define NHEADS 8
#define LALPHA 0.2f

__device__ __forceinline__ float elu1(float x)  { return x > 0.f ? x : __expf(x) - 1.f; }

// monotone float -> uint mapping (total order refines float order); ok(-v) == ~ok(v)
__device__ __forceinline__ unsigned ordkey(float v) {
    unsigned u = __float_as_uint(v);
    return u ^ (((unsigned)((int)u >> 31)) | 0x80000000u);
}
__device__ __forceinline__ float unord(unsigned k) {
    unsigned u = (k & 0x80000000u) ? (k ^ 0x80000000u) : ~k;
    return __uint_as_float(u);
}

// inclusive 64-lane add-scan: 6 DPP ops (VALU pipe only). Fallback: shfl_up.
#if __has_builtin(__builtin_amdgcn_update_dpp)
__device__ __forceinline__ float wscan(float x, int lane) {
    int y;
    y = __builtin_amdgcn_update_dpp(0, __float_as_int(x), 0x111, 0xF, 0xF, true); x += __int_as_float(y); // row_shr:1
    y = __builtin_amdgcn_update_dpp(0, __float_as_int(x), 0x112, 0xF, 0xF, true); x += __int_as_float(y); // row_shr:2
    y = __builtin_amdgcn_update_dpp(0, __float_as_int(x), 0x114, 0xF, 0xF, true); x += __int_as_float(y); // row_shr:4
    y = __builtin_amdgcn_update_dpp(0, __float_as_int(x), 0x118, 0xF, 0xF, true); x += __int_as_float(y); // row_shr:8
    y = __builtin_amdgcn_update_dpp(0, __float_as_int(x), 0x142, 0xA, 0xF, true); x += __int_as_float(y); // row_bcast:15, rows 1,3
    y = __builtin_amdgcn_update_dpp(0, __float_as_int(x), 0x143, 0xC, 0xF, true); x += __int_as_float(y); // row_bcast:31, rows 2,3
    return x;
}
#else
__device__ __forceinline__ float wscan(float x, int lane) {
    #pragma unroll
    for (int s = 1; s < 64; s <<= 1) {
        float y = __shfl_up(x, (unsigned)s, 64);
        x += (lane >= s) ? y : 0.f;
    }
    return x;
}
#endif

__device__ __forceinline__ unsigned long long shflxor64(unsigned long long x, int j) {
    unsigned lo = (unsigned)__shfl_xor((int)(unsigned)x, j, 64);
    unsigned hw = (unsigned)__shfl_xor((int)(unsigned)(x >> 32), j, 64);
    return (((unsigned long long)hw) << 32) | lo;
}

// branchless lower bound on ascending 512-long u64 LDS array: returns #{a[i] < v}
__device__ __forceinline__ int lb512u64(const unsigned long long* a, unsigned long long v) {
    int lo = 0;
    #pragma unroll
    for (int s = NN / 2; s >= 1; s >>= 1)
        if (a[lo + s - 1] < v) lo += s;
    return lo;
}

// bitonic sort of 512 u64 keys; thread r holds element r; lds = scratch + sorted output.
// Barrier-uniform: ALL threads of the block must call this (inactive ones just sync).
__device__ __forceinline__ unsigned long long sortnet512(
        unsigned long long x, unsigned long long* lds, int r, bool active) {
    #pragma unroll
    for (int k = 2; k <= NN; k <<= 1) {
        #pragma unroll
        for (int j = k >> 1; j >= 1; j >>= 1) {
            unsigned long long y;
            if (j >= 64) {                     // compile-time branch
                if (active) lds[r] = x;        // own slot only
                __syncthreads();
                y = active ? lds[r ^ j] : 0ull;
                __syncthreads();
            } else {
                y = shflxor64(x, j);
            }
            if (active) {
                const bool takeMin = ((r & j) == 0) == ((r & k) == 0);
                const bool sw = takeMin ? (y < x) : (x < y);
                x = sw ? y : x;
            }
        }
    }
    if (active) lds[r] = x;
    __syncthreads();
    return x;
}

// Fused layer-1 GAT per (b,h). 1024 threads: P (t<512) and H (t>=512) run different phases.
__global__ __launch_bounds__(1024) void k12_gat1(
        const float* __restrict__ nf, const float* __restrict__ Ws,
        const float* __restrict__ As, float* __restrict__ x)
{
    __shared__ __align__(16) float WT[NHID * NFEAT];           // transposed W [d][f], 4 KB
    __shared__ float aL[16];
    __shared__ __align__(16) float whL[NN][NHID];              // 16 KB
    __shared__ __align__(16) float part[NN][NHID];             // 16 KB
    __shared__ __align__(16) unsigned long long key1L[NN];     // 4 KB (sorted s1 keys)
    __shared__ __align__(16) unsigned long long key2L[NN];     // 4 KB (sorted s2 keys)
    __shared__ float prefP[NN], prefQ[NN], denS[NN];
    __shared__ __align__(16) float PP[NN][NHID];               // 16 KB
    __shared__ __align__(16) float QQ[NN][NHID];               // 16 KB
    __shared__ __align__(16) float wvT[16][NHID];

    const int blk = blockIdx.x;
    const int b = blk & 31, h = blk >> 5;   // same-b blocks share an XCD
    const int t = threadIdx.x;
    const int r = t & (NN - 1);
    const bool hi = t >= NN;
    const int lane = t & 63, w = t >> 6;

    {
        const int f = t >> 3, d = t & 7;
        WT[d * NFEAT + f] = Ws[(size_t)h * NFEAT * NHID + t];
    }
    if (t < 16) aL[t] = As[h * 16 + t];
    __syncthreads();                                           // B1

    // ---- matmul, split K: P cols [0,64), H cols [64,128) ----
    float acc[NHID];
    {
        #pragma unroll
        for (int d = 0; d < NHID; ++d) acc[d] = 0.f;
        const float4* row = (const float4*)(nf + ((size_t)b * NN + r) * NFEAT + (hi ? 64 : 0));
        const int fb = hi ? 16 : 0;
        const float4* WT4 = (const float4*)WT;
        #pragma unroll 4
        for (int f4 = 0; f4 < 16; ++f4) {
            float4 v = row[f4];
            #pragma unroll
            for (int d = 0; d < NHID; ++d) {
                float4 wv = WT4[d * 32 + fb + f4];
                acc[d] += v.x * wv.x + v.y * wv.y + v.z * wv.z + v.w * wv.w;
            }
        }
        if (hi) {
            float4* pp = (float4*)&part[r][0];
            pp[0] = make_float4(acc[0], acc[1], acc[2], acc[3]);
            pp[1] = make_float4(acc[4], acc[5], acc[6], acc[7]);
        }
    }
    __syncthreads();                                           // B2

    float v1 = 0.f;
    unsigned long long sk = 0ull;
    if (!hi) {
        #pragma unroll
        for (int d = 0; d < NHID; ++d) acc[d] += part[t][d];
        float a1 = 0.f, a2 = 0.f;
        #pragma unroll
        for (int d = 0; d < NHID; ++d) { a1 += acc[d] * aL[d]; a2 += acc[d] * aL[8 + d]; }
        v1 = a1;
        float4* wr = (float4*)&whL[t][0];
        wr[0] = make_float4(acc[0], acc[1], acc[2], acc[3]);
        wr[1] = make_float4(acc[4], acc[5], acc[6], acc[7]);
        sk = (((unsigned long long)ordkey(a1)) << 9) | (unsigned)t;
        key2L[t] = (((unsigned long long)ordkey(a2)) << 9) | (unsigned)t;
    }
    __syncthreads();                                           // B3
    if (hi) sk = key2L[r];

    // ---- concurrent bitonic sorts: P sorts key1, H sorts key2 ----
    sk = sortnet512(sk, hi ? key2L : key1L, r, true);

    // ---- P: exp scans + c4 search; H: payload-row gather + kH search ----
    float ps = 0.f, qs = 0.f;
    float who[NHID];
    float s2r = 0.f, e1p = 0.f, e1q = 0.f;
    int kH = 0, c4 = 0;
    if (!hi) {
        const float s1v = unord((unsigned)(sk >> 9));
        ps = wscan(__expf(s1v), lane);
        qs = wscan(__expf(LALPHA * s1v), lane);
        if (lane == 63) { wvT[w][0] = ps; wvT[w][1] = qs; }
        c4 = lb512u64(key2L, ((unsigned long long)(~ordkey(v1))) << 9);
        e1p = __expf(v1); e1q = __expf(LALPHA * v1);
    } else {
        s2r = unord((unsigned)(sk >> 9));
        const int j = (int)(sk & 511u);
        const float4 w0 = ((const float4*)&whL[j][0])[0];
        const float4 w1 = ((const float4*)&whL[j][0])[1];
        who[0] = w0.x; who[1] = w0.y; who[2] = w0.z; who[3] = w0.w;
        who[4] = w1.x; who[5] = w1.y; who[6] = w1.z; who[7] = w1.w;
        kH = lb512u64(key1L, ((unsigned long long)(~(unsigned)(sk >> 9))) << 9);
    }
    __syncthreads();                                           // B5

    if (!hi) {
        float offp = 0.f, offq = 0.f;
        #pragma unroll
        for (int ww = 0; ww < 8; ++ww) {
            const float tp = wvT[ww][0], tq = wvT[ww][1];
            if (ww < w) { offp += tp; offq += tq; }
        }
        prefP[t] = ps + offp;
        prefQ[t] = qs + offq;
    }
    __syncthreads();                                           // B6

    // ---- H: denominators; P: pre-gather own payload row ----
    float pw = 0.f;
    if (hi) {
        const float TPh = prefP[NN - 1];
        const float pk = kH ? prefP[kH - 1] : 0.f;
        const float qk = kH ? prefQ[kH - 1] : 0.f;
        const float den = __expf(s2r) * (TPh - pk) + __expf(LALPHA * s2r) * qk;
        denS[r] = den;
        pw = __expf(LALPHA * s2r) / den;
    } else {
        const unsigned long long k2 = key2L[t];
        const float s2p = unord((unsigned)(k2 >> 9));
        const int j2 = (int)(k2 & 511u);
        const float4 w0 = ((const float4*)&whL[j2][0])[0];
        const float4 w1 = ((const float4*)&whL[j2][0])[1];
        who[0] = w0.x; who[1] = w0.y; who[2] = w0.z; who[3] = w0.w;
        who[4] = w1.x; who[5] = w1.y; who[6] = w1.z; who[7] = w1.w;
        pw = __expf(s2p);
    }
    __syncthreads();                                           // B7

    // ---- payload scans: P scans P-components, H scans Q-components ----
    float pv[NHID];
    if (!hi) pw /= denS[t];
    #pragma unroll
    for (int c = 0; c < NHID; ++c) pv[c] = wscan(pw * who[c], lane);
    if (lane == 63) {
        float4* wp = (float4*)&wvT[w][0];
        wp[0] = make_float4(pv[0], pv[1], pv[2], pv[3]);
        wp[1] = make_float4(pv[4], pv[5], pv[6], pv[7]);
    }
    __syncthreads();                                           // B8

    float tot[NHID];
    {
        const int wb = hi ? 8 : 0;
        float off[NHID];
        #pragma unroll
        for (int c = 0; c < NHID; ++c) { off[c] = 0.f; tot[c] = 0.f; }
        #pragma unroll
        for (int ww = 0; ww < 8; ++ww) {
            const float4 t0 = ((const float4*)&wvT[wb + ww][0])[0];
            const float4 t1 = ((const float4*)&wvT[wb + ww][0])[1];
            tot[0] += t0.x; tot[1] += t0.y; tot[2] += t0.z; tot[3] += t0.w;
            tot[4] += t1.x; tot[5] += t1.y; tot[6] += t1.z; tot[7] += t1.w;
            if (wb + ww < w) {
                off[0] += t0.x; off[1] += t0.y; off[2] += t0.z; off[3] += t0.w;
                off[4] += t1.x; off[5] += t1.y; off[6] += t1.z; off[7] += t1.w;
            }
        }
        #pragma unroll
        for (int c = 0; c < NHID; ++c) pv[c] += off[c];
        float4* dst = hi ? (float4*)&QQ[r][0] : (float4*)&PP[r][0];
        dst[0] = make_float4(pv[0], pv[1], pv[2], pv[3]);
        dst[1] = make_float4(pv[4], pv[5], pv[6], pv[7]);
    }
    __syncthreads();                                           // B9

    // ---- P: row outputs ----
    if (!hi) {
        float4 P0, P1, Q0, Q1;
        if (c4 > 0) {
            const float4* pp4 = (const float4*)&PP[c4 - 1][0];
            const float4* qq4 = (const float4*)&QQ[c4 - 1][0];
            P0 = pp4[0]; P1 = pp4[1]; Q0 = qq4[0]; Q1 = qq4[1];
        } else {
            P0 = P1 = Q0 = Q1 = make_float4(0.f, 0.f, 0.f, 0.f);
        }
        float h0 = e1p * (tot[0] - P0.x) + e1q * Q0.x;
        float h1 = e1p * (tot[1] - P0.y) + e1q * Q0.y;
        float h2 = e1p * (tot[2] - P0.z) + e1q * Q0.z;
        float h3 = e1p * (tot[3] - P0.w) + e1q * Q0.w;
        float h4 = e1p * (tot[4] - P1.x) + e1q * Q1.x;
        float h5 = e1p * (tot[5] - P1.y) + e1q * Q1.y;
        float h6 = e1p * (tot[6] - P1.z) + e1q * Q1.z;
        float h7 = e1p * (tot[7] - P1.w) + e1q * Q1.w;
        float* xp = x + ((size_t)(b * NN + t)) * (NHEADS * NHID) + h * NHID;
        ((float4*)xp)[0] = make_float4(elu1(h0), elu1(h1), elu1(h2), elu1(h3));
        ((float4*)xp)[1] = make_float4(elu1(h4), elu1(h5), elu1(h6), elu1(h7));
    }
}

// Tail per batch b: Wh2 = x@W_out; bitonic sort of s1 (P) + c3 search (H); row-0 attn; head.
__global__ __launch_bounds__(1024) void k34_tail(
        const float* __restrict__ x, const float* __restrict__ Wout,
        const float* __restrict__ aout, const float* __restrict__ feats,
        const float* __restrict__ l1w, const float* __restrict__ l1b,
        const float* __restrict__ pa, const float* __restrict__ gma,
        const float* __restrict__ bta, const float* __restrict__ l2w,
        const float* __restrict__ l2b, float* __restrict__ out)
{
    __shared__ __align__(16) float WLT[NHID * 64];             // transposed W_out [d][f], 2 KB
    __shared__ float aL[16];
    __shared__ __align__(16) float wh2[NN][NHID];              // 16 KB
    __shared__ __align__(16) float part[NN][NHID];             // 16 KB
    __shared__ __align__(16) unsigned long long key1L[NN];     // 4 KB
    __shared__ float s2L[NN];
    __shared__ float prefP[NN], prefQ[NN];
    __shared__ float wvT[8][2];
    __shared__ float wR[8][NHID];
    __shared__ float hp[2][NHID];
    __shared__ float gatL[NHID];
    __shared__ float zL[NHID];
    __shared__ float s1zero;

    const int b = blockIdx.x, t = threadIdx.x;
    const int r = t & (NN - 1);
    const bool hi = t >= NN;
    const int lane = t & 63, w = t >> 6;

    if (t < 512) {
        const int f = t >> 3, d = t & 7;
        WLT[d * 64 + f] = Wout[t];
    }
    if (t < 16) aL[t] = aout[t];
    __syncthreads();                                           // B1

    // matmul, split K: P cols [0,32), H cols [32,64)
    float acc[NHID];
    {
        #pragma unroll
        for (int d = 0; d < NHID; ++d) acc[d] = 0.f;
        const float4* row = (const float4*)(x + ((size_t)b * NN + r) * (NHEADS * NHID) + (hi ? 32 : 0));
        const int fb = hi ? 8 : 0;
        const float4* WT4 = (const float4*)WLT;
        #pragma unroll 4
        for (int f4 = 0; f4 < 8; ++f4) {
            float4 v = row[f4];
            #pragma unroll
            for (int d = 0; d < NHID; ++d) {
                float4 wv = WT4[d * 16 + fb + f4];
                acc[d] += v.x * wv.x + v.y * wv.y + v.z * wv.z + v.w * wv.w;
            }
        }
        if (hi) {
            float4* pp = (float4*)&part[r][0];
            pp[0] = make_float4(acc[0], acc[1], acc[2], acc[3]);
            pp[1] = make_float4(acc[4], acc[5], acc[6], acc[7]);
        }
    }
    __syncthreads();                                           // B2

    unsigned long long sk = 0ull;
    if (!hi) {
        #pragma unroll
        for (int d = 0; d < NHID; ++d) acc[d] += part[t][d];
        float a1 = 0.f, a2 = 0.f;
        #pragma unroll
        for (int d = 0; d < NHID; ++d) { a1 += acc[d] * aL[d]; a2 += acc[d] * aL[8 + d]; }
        float4* wr = (float4*)&wh2[t][0];
        wr[0] = make_float4(acc[0], acc[1], acc[2], acc[3]);
        wr[1] = make_float4(acc[4], acc[5], acc[6], acc[7]);
        sk = (((unsigned long long)ordkey(a1)) << 9) | (unsigned)t;
        s2L[t] = a2;
        if (t == 0) s1zero = a1;
    }
    __syncthreads();                                           // B3

    sk = sortnet512(sk, key1L, r, !hi);

    // P: exp scans; H: c3 search
    float ps = 0.f, qs = 0.f;
    int c3 = 0; float v2h = 0.f;
    if (!hi) {
        const float s1v = unord((unsigned)(sk >> 9));
        ps = wscan(__expf(s1v), lane);
        qs = wscan(__expf(LALPHA * s1v), lane);
        if (lane == 63) { wvT[w][0] = ps; wvT[w][1] = qs; }
    } else {
        v2h = s2L[r];
        c3 = lb512u64(key1L, ((unsigned long long)(~ordkey(v2h))) << 9);
    }
    __syncthreads();                                           // B5

    if (!hi) {
        float offp = 0.f, offq = 0.f;
        #pragma unroll
        for (int ww = 0; ww < 8; ++ww) {
            const float tp = wvT[ww][0], tq = wvT[ww][1];
            if (ww < w) { offp += tp; offq += tq; }
        }
        prefP[t] = ps + offp;
        prefQ[t] = qs + offq;
    }
    __syncthreads();                                           // B6

    // H: den + row-0 weight + weighted wave-reduce;  P(t<128): head feats dot
    if (hi) {
        const float TPh = prefP[NN - 1];
        const float pk = c3 ? prefP[c3 - 1] : 0.f;
        const float qk = c3 ? prefQ[c3 - 1] : 0.f;
        const float dj = __expf(v2h) * (TPh - pk) + __expf(LALPHA * v2h) * qk;
        float e0 = s1zero + v2h;
        e0 = e0 >= 0.f ? e0 : LALPHA * e0;
        const float wgt = __expf(e0) / dj;
        float a[NHID];
        const float4 q0 = ((const float4*)&wh2[r][0])[0];
        const float4 q1 = ((const float4*)&wh2[r][0])[1];
        a[0] = wgt * q0.x; a[1] = wgt * q0.y; a[2] = wgt * q0.z; a[3] = wgt * q0.w;
        a[4] = wgt * q1.x; a[5] = wgt * q1.y; a[6] = wgt * q1.z; a[7] = wgt * q1.w;
        #pragma unroll
        for (int s = 1; s < 64; s <<= 1) {
            #pragma unroll
            for (int d = 0; d < NHID; ++d) a[d] += __shfl_xor(a[d], s, 64);
        }
        if (lane == 0) {
            #pragma unroll
            for (int d = 0; d < NHID; ++d) wR[w - 8][d] = a[d];
        }
    } else if (t < 128) {
        const float fk = feats[b * NFEAT + t];
        #pragma unroll
        for (int d = 0; d < NHID; ++d) {
            float p = fk * l1w[d * (NFEAT + NHID) + t];
            #pragma unroll
            for (int s = 1; s < 64; s <<= 1) p += __shfl_xor(p, s, 64);
            if (lane == 0) hp[w][d] = p;
        }
    }
    __syncthreads();                                           // B7

    if (t < NHID) {
        float g = 0.f;
        #pragma unroll
        for (int ww = 0; ww < 8; ++ww) g += wR[ww][t];
        gatL[t] = elu1(g);
    }
    __syncthreads();                                           // B8

    if (t < NHID) {
        const float* wv = l1w + t * (NFEAT + NHID);
        float z = l1b[t] + hp[0][t] + hp[1][t];
        #pragma unroll
        for (int k = 0; k < NHID; ++k) z += gatL[k] * wv[NFEAT + k];
        const float a = pa[0];
        z = z >= 0.f ? z : a * z;
        z = z * (1.f / sqrtf(1.f + 1e-5f)) * gma[t] + bta[t];
        zL[t] = z;
    }
    __syncthreads();                                           // B9
    if (t == 0) {
        float o = l2b[0];
        #pragma unroll
        for (int d = 0; d < NHID; ++d) o += zL[d] * l2w[d];
        out[b] = o;
    }
}

extern "C" void kernel_launch(void* const* d_in, const int* in_sizes, int n_in,
                              void* d_out, int out_size, void* d_ws, size_t ws_size,
                              hipStream_t stream) {
    const float* feats = (const float*)d_in[0];
    const float* nf    = (const float*)d_in[1];
    const float* Ws    = (const float*)d_in[2];
    const float* As    = (const float*)d_in[3];
    const float* Wout  = (const float*)d_in[4];
    const float* aout  = (const float*)d_in[5];
    const float* l1w   = (const float*)d_in[6];
    const float* l1b   = (const float*)d_in[7];
    const float* pa    = (const float*)d_in[8];
    const float* gma   = (const float*)d_in[9];
    const float* bta   = (const float*)d_in[10];
    const float* l2w   = (const float*)d_in[11];
    const float* l2b   = (const float*)d_in[12];
    float* out = (float*)d_out;

    float* x = (float*)d_ws;   // 32*512*64 floats = 4 MB

    k12_gat1<<<BB * NHEADS, 1024, 0, stream>>>(nf, Ws, As, x);
    k34_tail<<<BB, 1024, 0, stream>>>(x, Wout, aout, feats, l1w, l1b, pa, gma, bta, l2w, l2b, out);
}

// Round 7
// 39.723 us; speedup vs baseline: 1.6678x; 1.0111x over previous
//
#include <hip/hip_runtime.h>
#include <math.h>

#define BB 32
#define NN 512
#define NFEAT 128
#define NHID 8
#define NHEADS 8
#define LALPHA 0.2f

__device__ __forceinline__ float elu1(float x)  { return x > 0.f ? x : __expf(x) - 1.f; }

// monotone float -> uint mapping (total order refines float order); ok(-v) == ~ok(v)
__device__ __forceinline__ unsigned ordkey(float v) {
    unsigned u = __float_as_uint(v);
    return u ^ (((unsigned)((int)u >> 31)) | 0x80000000u);
}
__device__ __forceinline__ float unord(unsigned k) {
    unsigned u = (k & 0x80000000u) ? (k ^ 0x80000000u) : ~k;
    return __uint_as_float(u);
}

// inclusive 64-lane add-scan: 6 DPP ops (VALU pipe only).
#if __has_builtin(__builtin_amdgcn_update_dpp)
__device__ __forceinline__ float wscan(float x, int lane) {
    int y;
    y = __builtin_amdgcn_update_dpp(0, __float_as_int(x), 0x111, 0xF, 0xF, true); x += __int_as_float(y);
    y = __builtin_amdgcn_update_dpp(0, __float_as_int(x), 0x112, 0xF, 0xF, true); x += __int_as_float(y);
    y = __builtin_amdgcn_update_dpp(0, __float_as_int(x), 0x114, 0xF, 0xF, true); x += __int_as_float(y);
    y = __builtin_amdgcn_update_dpp(0, __float_as_int(x), 0x118, 0xF, 0xF, true); x += __int_as_float(y);
    y = __builtin_amdgcn_update_dpp(0, __float_as_int(x), 0x142, 0xA, 0xF, true); x += __int_as_float(y);
    y = __builtin_amdgcn_update_dpp(0, __float_as_int(x), 0x143, 0xC, 0xF, true); x += __int_as_float(y);
    return x;
}
#else
__device__ __forceinline__ float wscan(float x, int lane) {
    #pragma unroll
    for (int s = 1; s < 64; s <<= 1) {
        float y = __shfl_up(x, (unsigned)s, 64);
        x += (lane >= s) ? y : 0.f;
    }
    return x;
}
#endif

__device__ __forceinline__ unsigned long long shflxor64(unsigned long long x, int j) {
    unsigned lo = (unsigned)__shfl_xor((int)(unsigned)x, j, 64);
    unsigned hw = (unsigned)__shfl_xor((int)(unsigned)(x >> 32), j, 64);
    return (((unsigned long long)hw) << 32) | lo;
}

// full in-wave bitonic sort of 64 u64 keys (ascending across lanes), register-only
__device__ __forceinline__ unsigned long long wsort64(unsigned long long x, int lane) {
    #pragma unroll
    for (int k = 2; k <= 64; k <<= 1) {
        #pragma unroll
        for (int j = k >> 1; j >= 1; j >>= 1) {
            unsigned long long y = shflxor64(x, j);
            const bool takeMin = ((lane & j) == 0) == ((lane & k) == 0);
            const bool sw = takeMin ? (y < x) : (x < y);
            x = sw ? y : x;
        }
    }
    return x;
}

// guarded branchless lower bounds (can return the full length)
__device__ __forceinline__ int lb64u(const unsigned long long* a, unsigned long long v) {
    int lo = 0;
    #pragma unroll
    for (int s = 64; s >= 1; s >>= 1) {
        const int i2 = lo + s - 1;
        if (i2 < 64 && a[i2] < v) lo += s;
    }
    return lo;
}
__device__ __forceinline__ int lb512u(const unsigned long long* a, unsigned long long v) {
    int lo = 0;
    #pragma unroll
    for (int s = NN; s >= 1; s >>= 1) {
        const int i2 = lo + s - 1;
        if (i2 < NN && a[i2] < v) lo += s;
    }
    return lo;
}

// global rank of x within the 8 sorted runs (own wave-run index wr, own lane pos = lane)
__device__ __forceinline__ int rank512(const unsigned long long* runs, unsigned long long x,
                                       int wr, int lane) {
    int rk = lane;
    #pragma unroll
    for (int w2 = 0; w2 < 8; ++w2)
        if (w2 != wr) rk += lb64u(runs + 64 * w2, x);
    return rk;
}

// Fused layer-1 GAT per (b,h). 1024 threads: P (t<512) and H (t>=512) run different phases.
__global__ __launch_bounds__(1024) void k12_gat1(
        const float* __restrict__ nf, const float* __restrict__ Ws,
        const float* __restrict__ As, float* __restrict__ x)
{
    __shared__ __align__(16) float WT[NHID * NFEAT];           // transposed W [d][f], 4 KB
    __shared__ float aL[16];
    __shared__ __align__(16) float whL[NN][NHID];              // 16 KB
    __shared__ __align__(16) float part[NN][NHID];             // 16 KB
    __shared__ __align__(16) unsigned long long key1L[NN];     // 4 KB (unsorted->sorted s1 keys)
    __shared__ __align__(16) unsigned long long key2L[NN];     // 4 KB (unsorted->sorted s2 keys)
    __shared__ __align__(16) unsigned long long keyR1[NN];     // 4 KB (8 sorted runs)
    __shared__ __align__(16) unsigned long long keyR2[NN];     // 4 KB
    __shared__ float prefP[NN], prefQ[NN], denS[NN];
    __shared__ __align__(16) float PP[NN][NHID];               // 16 KB
    __shared__ __align__(16) float QQ[NN][NHID];               // 16 KB
    __shared__ __align__(16) float wvT[16][NHID];

    const int blk = blockIdx.x;
    const int b = blk & 31, h = blk >> 5;   // same-b blocks share an XCD
    const int t = threadIdx.x;
    const int r = t & (NN - 1);
    const bool hi = t >= NN;
    const int lane = t & 63, w = t >> 6;
    const int wr = w & 7;                   // run index within own half

    {
        const int f = t >> 3, d = t & 7;
        WT[d * NFEAT + f] = Ws[(size_t)h * NFEAT * NHID + t];
    }
    if (t < 16) aL[t] = As[h * 16 + t];
    __syncthreads();                                           // B1

    // ---- matmul, split K: P cols [0,64), H cols [64,128) ----
    float acc[NHID];
    {
        #pragma unroll
        for (int d = 0; d < NHID; ++d) acc[d] = 0.f;
        const float4* row = (const float4*)(nf + ((size_t)b * NN + r) * NFEAT + (hi ? 64 : 0));
        const int fb = hi ? 16 : 0;
        const float4* WT4 = (const float4*)WT;
        #pragma unroll 4
        for (int f4 = 0; f4 < 16; ++f4) {
            float4 v = row[f4];
            #pragma unroll
            for (int d = 0; d < NHID; ++d) {
                float4 wv = WT4[d * 32 + fb + f4];
                acc[d] += v.x * wv.x + v.y * wv.y + v.z * wv.z + v.w * wv.w;
            }
        }
        if (hi) {
            float4* pp = (float4*)&part[r][0];
            pp[0] = make_float4(acc[0], acc[1], acc[2], acc[3]);
            pp[1] = make_float4(acc[4], acc[5], acc[6], acc[7]);
        }
    }
    __syncthreads();                                           // B2

    float v1 = 0.f;
    unsigned long long sk = 0ull;
    if (!hi) {
        #pragma unroll
        for (int d = 0; d < NHID; ++d) acc[d] += part[t][d];
        float a1 = 0.f, a2 = 0.f;
        #pragma unroll
        for (int d = 0; d < NHID; ++d) { a1 += acc[d] * aL[d]; a2 += acc[d] * aL[8 + d]; }
        v1 = a1;
        float4* wrp = (float4*)&whL[t][0];
        wrp[0] = make_float4(acc[0], acc[1], acc[2], acc[3]);
        wrp[1] = make_float4(acc[4], acc[5], acc[6], acc[7]);
        sk = (((unsigned long long)ordkey(a1)) << 9) | (unsigned)t;
        key2L[t] = (((unsigned long long)ordkey(a2)) << 9) | (unsigned)t;
    }
    __syncthreads();                                           // B3

    // ---- wave-local sorts (register-only), write sorted runs ----
    if (hi) sk = key2L[r];
    sk = wsort64(sk, lane);
    if (!hi) keyR1[t] = sk; else keyR2[r] = sk;
    __syncthreads();                                           // B4

    // ---- rank-merge + scatter into final sorted arrays ----
    {
        const unsigned long long* runs = hi ? keyR2 : keyR1;
        const int rk = rank512(runs, sk, wr, lane);
        if (!hi) key1L[rk] = sk; else key2L[rk] = sk;
    }
    __syncthreads();                                           // B5

    // ---- P: exp scans + c4; H: own sorted element, payload gather + kH ----
    float ps = 0.f, qs = 0.f;
    float who[NHID];
    float s2r = 0.f, e2p = 0.f, e2q = 0.f, e1p = 0.f, e1q = 0.f;
    int kH = 0, c4 = 0;
    if (!hi) {
        const float s1v = unord((unsigned)(key1L[t] >> 9));
        ps = wscan(__expf(s1v), lane);
        qs = wscan(__expf(LALPHA * s1v), lane);
        if (lane == 63) { wvT[w][0] = ps; wvT[w][1] = qs; }
        c4 = lb512u(key2L, ((unsigned long long)(~ordkey(v1))) << 9);
        e1p = __expf(v1); e1q = __expf(LALPHA * v1);
    } else {
        const unsigned long long k2 = key2L[r];
        s2r = unord((unsigned)(k2 >> 9));
        const int j = (int)(k2 & 511u);
        const float4 w0 = ((const float4*)&whL[j][0])[0];
        const float4 w1 = ((const float4*)&whL[j][0])[1];
        who[0] = w0.x; who[1] = w0.y; who[2] = w0.z; who[3] = w0.w;
        who[4] = w1.x; who[5] = w1.y; who[6] = w1.z; who[7] = w1.w;
        kH = lb512u(key1L, ((unsigned long long)(~(unsigned)(k2 >> 9))) << 9);
        e2p = __expf(s2r); e2q = __expf(LALPHA * s2r);
    }
    __syncthreads();                                           // B6

    // ---- P: finalize prefixes + pre-gather own payload row ----
    float pw = 0.f;
    if (!hi) {
        float offp = 0.f, offq = 0.f;
        #pragma unroll
        for (int ww = 0; ww < 8; ++ww) {
            const float tp = wvT[ww][0], tq = wvT[ww][1];
            if (ww < w) { offp += tp; offq += tq; }
        }
        prefP[t] = ps + offp;
        prefQ[t] = qs + offq;
        const unsigned long long k2 = key2L[t];
        const float s2p = unord((unsigned)(k2 >> 9));
        const int j2 = (int)(k2 & 511u);
        const float4 w0 = ((const float4*)&whL[j2][0])[0];
        const float4 w1 = ((const float4*)&whL[j2][0])[1];
        who[0] = w0.x; who[1] = w0.y; who[2] = w0.z; who[3] = w0.w;
        who[4] = w1.x; who[5] = w1.y; who[6] = w1.z; who[7] = w1.w;
        pw = __expf(s2p);
    }
    __syncthreads();                                           // B7

    // ---- H: denominators ----
    if (hi) {
        const float TPh = prefP[NN - 1];
        const float pk = kH ? prefP[kH - 1] : 0.f;
        const float qk = kH ? prefQ[kH - 1] : 0.f;
        const float den = e2p * (TPh - pk) + e2q * qk;
        denS[r] = den;
        pw = e2q / den;
    }
    __syncthreads();                                           // B8

    // ---- payload scans: P scans P-components, H scans Q-components ----
    float pv[NHID];
    if (!hi) pw /= denS[t];
    #pragma unroll
    for (int c = 0; c < NHID; ++c) pv[c] = wscan(pw * who[c], lane);
    if (lane == 63) {
        float4* wp = (float4*)&wvT[w][0];
        wp[0] = make_float4(pv[0], pv[1], pv[2], pv[3]);
        wp[1] = make_float4(pv[4], pv[5], pv[6], pv[7]);
    }
    __syncthreads();                                           // B9

    float tot[NHID];
    {
        const int wb = hi ? 8 : 0;
        float off[NHID];
        #pragma unroll
        for (int c = 0; c < NHID; ++c) { off[c] = 0.f; tot[c] = 0.f; }
        #pragma unroll
        for (int ww = 0; ww < 8; ++ww) {
            const float4 t0 = ((const float4*)&wvT[wb + ww][0])[0];
            const float4 t1 = ((const float4*)&wvT[wb + ww][0])[1];
            tot[0] += t0.x; tot[1] += t0.y; tot[2] += t0.z; tot[3] += t0.w;
            tot[4] += t1.x; tot[5] += t1.y; tot[6] += t1.z; tot[7] += t1.w;
            if (wb + ww < w) {
                off[0] += t0.x; off[1] += t0.y; off[2] += t0.z; off[3] += t0.w;
                off[4] += t1.x; off[5] += t1.y; off[6] += t1.z; off[7] += t1.w;
            }
        }
        #pragma unroll
        for (int c = 0; c < NHID; ++c) pv[c] += off[c];
        float4* dst = hi ? (float4*)&QQ[r][0] : (float4*)&PP[r][0];
        dst[0] = make_float4(pv[0], pv[1], pv[2], pv[3]);
        dst[1] = make_float4(pv[4], pv[5], pv[6], pv[7]);
    }
    __syncthreads();                                           // B10

    // ---- P: row outputs ----
    if (!hi) {
        float4 P0, P1, Q0, Q1;
        if (c4 > 0) {
            const float4* pp4 = (const float4*)&PP[c4 - 1][0];
            const float4* qq4 = (const float4*)&QQ[c4 - 1][0];
            P0 = pp4[0]; P1 = pp4[1]; Q0 = qq4[0]; Q1 = qq4[1];
        } else {
            P0 = P1 = Q0 = Q1 = make_float4(0.f, 0.f, 0.f, 0.f);
        }
        float h0 = e1p * (tot[0] - P0.x) + e1q * Q0.x;
        float h1 = e1p * (tot[1] - P0.y) + e1q * Q0.y;
        float h2 = e1p * (tot[2] - P0.z) + e1q * Q0.z;
        float h3 = e1p * (tot[3] - P0.w) + e1q * Q0.w;
        float h4 = e1p * (tot[4] - P1.x) + e1q * Q1.x;
        float h5 = e1p * (tot[5] - P1.y) + e1q * Q1.y;
        float h6 = e1p * (tot[6] - P1.z) + e1q * Q1.z;
        float h7 = e1p * (tot[7] - P1.w) + e1q * Q1.w;
        float* xp = x + ((size_t)(b * NN + t)) * (NHEADS * NHID) + h * NHID;
        ((float4*)xp)[0] = make_float4(elu1(h0), elu1(h1), elu1(h2), elu1(h3));
        ((float4*)xp)[1] = make_float4(elu1(h4), elu1(h5), elu1(h6), elu1(h7));
    }
}

// Tail per batch b: Wh2 = x@W_out; wave-sort + rank-merge of s1; row-0 attn; head MLP.
__global__ __launch_bounds__(1024) void k34_tail(
        const float* __restrict__ x, const float* __restrict__ Wout,
        const float* __restrict__ aout, const float* __restrict__ feats,
        const float* __restrict__ l1w, const float* __restrict__ l1b,
        const float* __restrict__ pa, const float* __restrict__ gma,
        const float* __restrict__ bta, const float* __restrict__ l2w,
        const float* __restrict__ l2b, float* __restrict__ out)
{
    __shared__ __align__(16) float WLT[NHID * 64];             // transposed W_out [d][f], 2 KB
    __shared__ float aL[16];
    __shared__ __align__(16) float wh2[NN][NHID];              // 16 KB
    __shared__ __align__(16) float part[NN][NHID];             // 16 KB
    __shared__ __align__(16) unsigned long long key1L[NN];     // 4 KB
    __shared__ __align__(16) unsigned long long keyR1[NN];     // 4 KB
    __shared__ float s2L[NN];
    __shared__ float prefP[NN], prefQ[NN];
    __shared__ float wvT[8][2];
    __shared__ float wR[8][NHID];
    __shared__ float hp[2][NHID];
    __shared__ float gatL[NHID];
    __shared__ float zL[NHID];
    __shared__ float s1zero;

    const int b = blockIdx.x, t = threadIdx.x;
    const int r = t & (NN - 1);
    const bool hi = t >= NN;
    const int lane = t & 63, w = t >> 6;
    const int wr = w & 7;

    if (t < 512) {
        const int f = t >> 3, d = t & 7;
        WLT[d * 64 + f] = Wout[t];
    }
    if (t < 16) aL[t] = aout[t];
    __syncthreads();                                           // B1

    // matmul, split K: P cols [0,32), H cols [32,64)
    float acc[NHID];
    {
        #pragma unroll
        for (int d = 0; d < NHID; ++d) acc[d] = 0.f;
        const float4* row = (const float4*)(x + ((size_t)b * NN + r) * (NHEADS * NHID) + (hi ? 32 : 0));
        const int fb = hi ? 8 : 0;
        const float4* WT4 = (const float4*)WLT;
        #pragma unroll 4
        for (int f4 = 0; f4 < 8; ++f4) {
            float4 v = row[f4];
            #pragma unroll
            for (int d = 0; d < NHID; ++d) {
                float4 wv = WT4[d * 16 + fb + f4];
                acc[d] += v.x * wv.x + v.y * wv.y + v.z * wv.z + v.w * wv.w;
            }
        }
        if (hi) {
            float4* pp = (float4*)&part[r][0];
            pp[0] = make_float4(acc[0], acc[1], acc[2], acc[3]);
            pp[1] = make_float4(acc[4], acc[5], acc[6], acc[7]);
        }
    }
    __syncthreads();                                           // B2

    unsigned long long sk = 0ull;
    if (!hi) {
        #pragma unroll
        for (int d = 0; d < NHID; ++d) acc[d] += part[t][d];
        float a1 = 0.f, a2 = 0.f;
        #pragma unroll
        for (int d = 0; d < NHID; ++d) { a1 += acc[d] * aL[d]; a2 += acc[d] * aL[8 + d]; }
        float4* wrp = (float4*)&wh2[t][0];
        wrp[0] = make_float4(acc[0], acc[1], acc[2], acc[3]);
        wrp[1] = make_float4(acc[4], acc[5], acc[6], acc[7]);
        sk = (((unsigned long long)ordkey(a1)) << 9) | (unsigned)t;
        s2L[t] = a2;
        if (t == 0) s1zero = a1;
    }
    __syncthreads();                                           // B3

    // P: wave-sort + write runs;  H (r<128): head feats dot
    if (!hi) {
        sk = wsort64(sk, lane);
        keyR1[t] = sk;
    } else if (r < 128) {
        const float fk = feats[b * NFEAT + r];
        #pragma unroll
        for (int d = 0; d < NHID; ++d) {
            float p = fk * l1w[d * (NFEAT + NHID) + r];
            #pragma unroll
            for (int s = 1; s < 64; s <<= 1) p += __shfl_xor(p, s, 64);
            if (lane == 0) hp[w - 8][d] = p;
        }
    }
    __syncthreads();                                           // B4

    if (!hi) {
        const int rk = rank512(keyR1, sk, wr, lane);
        key1L[rk] = sk;
    }
    __syncthreads();                                           // B5

    // P: exp scans; H: c3 search
    float ps = 0.f, qs = 0.f;
    int c3 = 0; float v2h = 0.f, e2p = 0.f, e2q = 0.f;
    if (!hi) {
        const float s1v = unord((unsigned)(key1L[t] >> 9));
        ps = wscan(__expf(s1v), lane);
        qs = wscan(__expf(LALPHA * s1v), lane);
        if (lane == 63) { wvT[w][0] = ps; wvT[w][1] = qs; }
    } else {
        v2h = s2L[r];
        c3 = lb512u(key1L, ((unsigned long long)(~ordkey(v2h))) << 9);
        e2p = __expf(v2h); e2q = __expf(LALPHA * v2h);
    }
    __syncthreads();                                           // B6

    if (!hi) {
        float offp = 0.f, offq = 0.f;
        #pragma unroll
        for (int ww = 0; ww < 8; ++ww) {
            const float tp = wvT[ww][0], tq = wvT[ww][1];
            if (ww < w) { offp += tp; offq += tq; }
        }
        prefP[t] = ps + offp;
        prefQ[t] = qs + offq;
    }
    __syncthreads();                                           // B7

    // H: den + row-0 weight + weighted wave-reduce
    if (hi) {
        const float TPh = prefP[NN - 1];
        const float pk = c3 ? prefP[c3 - 1] : 0.f;
        const float qk = c3 ? prefQ[c3 - 1] : 0.f;
        const float dj = e2p * (TPh - pk) + e2q * qk;
        float e0 = s1zero + v2h;
        e0 = e0 >= 0.f ? e0 : LALPHA * e0;
        const float wgt = __expf(e0) / dj;
        float a[NHID];
        const float4 q0 = ((const float4*)&wh2[r][0])[0];
        const float4 q1 = ((const float4*)&wh2[r][0])[1];
        a[0] = wgt * q0.x; a[1] = wgt * q0.y; a[2] = wgt * q0.z; a[3] = wgt * q0.w;
        a[4] = wgt * q1.x; a[5] = wgt * q1.y; a[6] = wgt * q1.z; a[7] = wgt * q1.w;
        #pragma unroll
        for (int s = 1; s < 64; s <<= 1) {
            #pragma unroll
            for (int d = 0; d < NHID; ++d) a[d] += __shfl_xor(a[d], s, 64);
        }
        if (lane == 0) {
            #pragma unroll
            for (int d = 0; d < NHID; ++d) wR[w - 8][d] = a[d];
        }
    }
    __syncthreads();                                           // B8

    if (t < NHID) {
        float g = 0.f;
        #pragma unroll
        for (int ww = 0; ww < 8; ++ww) g += wR[ww][t];
        gatL[t] = elu1(g);
    }
    __syncthreads();                                           // B9

    if (t < NHID) {
        const float* wv = l1w + t * (NFEAT + NHID);
        float z = l1b[t] + hp[0][t] + hp[1][t];
        #pragma unroll
        for (int k = 0; k < NHID; ++k) z += gatL[k] * wv[NFEAT + k];
        const float a = pa[0];
        z = z >= 0.f ? z : a * z;
        z = z * (1.f / sqrtf(1.f + 1e-5f)) * gma[t] + bta[t];
        zL[t] = z;
    }
    __syncthreads();                                           // B10
    if (t == 0) {
        float o = l2b[0];
        #pragma unroll
        for (int d = 0; d < NHID; ++d) o += zL[d] * l2w[d];
        out[b] = o;
    }
}

extern "C" void kernel_launch(void* const* d_in, const int* in_sizes, int n_in,
                              void* d_out, int out_size, void* d_ws, size_t ws_size,
                              hipStream_t stream) {
    const float* feats = (const float*)d_in[0];
    const float* nf    = (const float*)d_in[1];
    const float* Ws    = (const float*)d_in[2];
    const float* As    = (const float*)d_in[3];
    const float* Wout  = (const float*)d_in[4];
    const float* aout  = (const float*)d_in[5];
    const float* l1w   = (const float*)d_in[6];
    const float* l1b   = (const float*)d_in[7];
    const float* pa    = (const float*)d_in[8];
    const float* gma   = (const float*)d_in[9];
    const float* bta   = (const float*)d_in[10];
    const float* l2w   = (const float*)d_in[11];
    const float* l2b   = (const float*)d_in[12];
    float* out = (float*)d_out;

    float* x = (float*)d_ws;   // 32*512*64 floats = 4 MB

    k12_gat1<<<BB * NHEADS, 1024, 0, stream>>>(nf, Ws, As, x);
    k34_tail<<<BB, 1024, 0, stream>>>(x, Wout, aout, feats, l1w, l1b, pa, gma, bta, l2w, l2b, out);
}